// Round 9
// baseline (337.296 us; speedup 1.0000x reference)
//
#include <hip/hip_runtime.h>
#include <math.h>

#define BATCHN 4096
#define DMODEL 1024
#define NT 64
#define RANK 8
#define K2 512   // NT*RANK

typedef __attribute__((ext_vector_type(8))) short bf16x8;
typedef __attribute__((ext_vector_type(4))) float f32x4;

__device__ __forceinline__ void async16(void* lds, const void* g) {
    __builtin_amdgcn_global_load_lds(
        (const __attribute__((address_space(1))) void*)g,
        (__attribute__((address_space(3))) void*)lds, 16, 0, 0);
}

__device__ __forceinline__ short f2bf_hu(float f) {   // round half-up
    unsigned u = __builtin_bit_cast(unsigned, f);
    return (short)((u + 0x8000u) >> 16);
}

__device__ __forceinline__ short f2bf(float f) {      // RNE
    unsigned u = __builtin_bit_cast(unsigned, f);
    u += 0x7fffu + ((u >> 16) & 1u);
    return (short)(u >> 16);
}

__device__ __forceinline__ bf16x8 cvt8(const float* __restrict__ p) {
    float4 v0 = *(const float4*)p;
    float4 v1 = *(const float4*)(p + 4);
    bf16x8 o;
    o[0] = f2bf_hu(v0.x); o[1] = f2bf_hu(v0.y); o[2] = f2bf_hu(v0.z); o[3] = f2bf_hu(v0.w);
    o[4] = f2bf_hu(v1.x); o[5] = f2bf_hu(v1.y); o[6] = f2bf_hu(v1.z); o[7] = f2bf_hu(v1.w);
    return o;
}

// Device-scope grid barrier. Bounded spin: on residency failure we produce a
// wrong answer (caught by harness) instead of a hang.
__device__ __forceinline__ void grid_barrier(unsigned* c, unsigned n) {
    __syncthreads();
    if (threadIdx.x == 0) {
        __threadfence();                               // release
        atomicAdd(c, 1u);
        unsigned spins = 0;
        while (__hip_atomic_load(c, __ATOMIC_RELAXED, __HIP_MEMORY_SCOPE_AGENT) < n) {
            __builtin_amdgcn_s_sleep(2);
            if (++spins > 1000000u) break;             // ~50 ms bailout
        }
        __threadfence();                               // acquire
    }
    __syncthreads();
}

// One persistent kernel, grid 1024 x 256, 32 KB LDS -> exactly 4 blocks/CU.
// Phase 0: convert x->xb, [enc;V]->Wb, U->Ub (bf16, coalesced, grid-stride)
// Phase 1: blocks 0..575 gate/vx GEMM (BM=64,BN=64,BK=128, async16 staging);
//          blocks 576..639 Frobenius norms
// Phase 2: all 1024 blocks: out GEMM (BM=64,BN=64,BK=128, async16 B staging)
__global__ __launch_bounds__(256, 4) void fused_kernel(
    const float* __restrict__ x, const float* __restrict__ V,
    const float* __restrict__ U, const float* __restrict__ enc,
    const float* __restrict__ bias,
    float* __restrict__ out, float* __restrict__ gate, float* __restrict__ fro,
    unsigned short* __restrict__ xb, unsigned short* __restrict__ Wb,
    unsigned short* __restrict__ Ub, unsigned short* __restrict__ vx,
    unsigned* __restrict__ counters)
{
    __shared__ unsigned short As[64 * 128];   // 16 KB
    __shared__ unsigned short Bs[64 * 128];   // 16 KB
    __shared__ float red[8];
    const int bid = blockIdx.x, t = threadIdx.x;
    const int wave = t >> 6, lane = t & 63;
    const int wm = wave & 1, wn = wave >> 1;
    const int l15 = lane & 15, lq = lane >> 4;

    // ---------- Phase 0: convert (5,308,416 elems = 663,552 bf16x8 chunks) ----------
    {
        const int tid = bid * 256 + t;
        for (int c = tid; c < 663552; c += 262144) {
            const float* src;
            unsigned short* dst;
            if (c < 524288) {                       // x
                src = x + (size_t)c * 8; dst = xb + (size_t)c * 8;
            } else if (c < 598016) {                // [enc;V] rows 0..575
                const int e = (c - 524288) * 8;
                const int row = e >> 10, col = e & 1023;
                src = (row < 64) ? (enc + (size_t)row * 1024 + col)
                                 : (V + (size_t)(row - 64) * 1024 + col);
                dst = Wb + e;
            } else {                                // U native [n][d][r]
                const int e = (c - 598016) * 8;
                src = U + e; dst = Ub + e;
            }
            *(bf16x8*)dst = cvt8(src);
        }
    }
    grid_barrier(&counters[0], (unsigned)gridDim.x);

    // ---------- Phase 1 ----------
    if (bid < 576) {
        const int bn = bid % 9, bm = bid / 9;
        f32x4 acc[2][2] = {};
        const size_t Abase = (size_t)bm * 64 * DMODEL;
        const size_t Bbase = (size_t)bn * 64 * DMODEL;
        for (int k0 = 0; k0 < DMODEL; k0 += 128) {
            #pragma unroll
            for (int c = 0; c < 4; ++c) {
                const int r0 = wave * 16 + c * 4;
                const int row = r0 + lq;
                const int g = l15 ^ (row & 15);
                async16(&As[r0 * 128], xb + Abase + (size_t)row * DMODEL + k0 + g * 8);
                async16(&Bs[r0 * 128], Wb + Bbase + (size_t)row * DMODEL + k0 + g * 8);
            }
            __syncthreads();
            #pragma unroll
            for (int s = 0; s < 4; ++s) {
                const int kc = s * 4 + lq;
                bf16x8 af[2], bfr[2];
                #pragma unroll
                for (int i = 0; i < 2; ++i) {
                    const int m = wm * 32 + i * 16 + l15;
                    af[i] = *(const bf16x8*)&As[m * 128 + ((kc ^ (m & 15)) * 8)];
                }
                #pragma unroll
                for (int j = 0; j < 2; ++j) {
                    const int n = wn * 32 + j * 16 + l15;
                    bfr[j] = *(const bf16x8*)&Bs[n * 128 + ((kc ^ (n & 15)) * 8)];
                }
                #pragma unroll
                for (int i = 0; i < 2; ++i)
                    #pragma unroll
                    for (int j = 0; j < 2; ++j)
                        acc[i][j] = __builtin_amdgcn_mfma_f32_16x16x32_bf16(
                            af[i], bfr[j], acc[i][j], 0, 0, 0);
            }
            __syncthreads();
        }
        #pragma unroll
        for (int i = 0; i < 2; ++i) {
            const int rowb = bm * 64 + wm * 32 + i * 16 + lq * 4;
            #pragma unroll
            for (int j = 0; j < 2; ++j) {
                const int col = wn * 32 + j * 16 + l15;
                #pragma unroll
                for (int r = 0; r < 4; ++r) {
                    const int row = rowb + r;
                    const float v = acc[i][j][r];
                    if (bn == 0) {
                        const float p = v - bias[col];
                        gate[(size_t)row * NT + col] = p > 0.f ? p : 0.f;
                    } else {
                        vx[(size_t)row * K2 + (bn - 1) * 64 + col] = (unsigned short)f2bf(v);
                    }
                }
            }
        }
    } else if (bid < 640) {
        const int n = bid - 576;
        const float* Up = U + (size_t)n * (DMODEL * RANK);
        const float* Vp = V + (size_t)n * (DMODEL * RANK);
        float su = 0.f, sv = 0.f;
        for (int i = t * 4; i < DMODEL * RANK; i += 1024) {
            float4 a = *(const float4*)(Up + i);
            su += a.x * a.x + a.y * a.y + a.z * a.z + a.w * a.w;
            float4 b = *(const float4*)(Vp + i);
            sv += b.x * b.x + b.y * b.y + b.z * b.z + b.w * b.w;
        }
        #pragma unroll
        for (int off = 32; off; off >>= 1) {
            su += __shfl_down(su, off);
            sv += __shfl_down(sv, off);
        }
        if ((t & 63) == 0) { red[wave * 2] = su; red[wave * 2 + 1] = sv; }
        __syncthreads();
        if (t == 0) {
            float tu = red[0] + red[2] + red[4] + red[6];
            float tv = red[1] + red[3] + red[5] + red[7];
            fro[n] = sqrtf(tu) * sqrtf(tv) / sqrtf((float)(DMODEL * RANK));
        }
    }
    grid_barrier(&counters[1], (unsigned)gridDim.x);

    // ---------- Phase 2: out = (gate ⊙ vx) @ Ub^T ----------
    {
        const int bn = bid & 15, bm = bid >> 4;
        f32x4 acc[2][2] = {};
        for (int k0 = 0; k0 < K2; k0 += 128) {
            const int nb = k0 >> 3;
            // A: gated vx (bf16 in, fp32 gate, bf16 out), swizzled chunks
            #pragma unroll
            for (int i = 0; i < 4; ++i) {
                const int row = wave * 16 + i * 4 + lq;
                const int grow = bm * 64 + row;
                const int g = l15 ^ (row & 15);
                bf16x8 v = *(const bf16x8*)(vx + (size_t)grow * K2 + k0 + g * 8);
                const float gs = gate[(size_t)grow * NT + nb + g];
                bf16x8 o;
                #pragma unroll
                for (int e = 0; e < 8; ++e) {
                    const float f = __builtin_bit_cast(float,
                        ((unsigned)(unsigned short)v[e]) << 16);
                    o[e] = (short)(__builtin_bit_cast(unsigned, f * gs) >> 16);  // trunc
                }
                *(bf16x8*)&As[row * 128 + l15 * 8] = o;
            }
            // B: async16 from Ub bf16 native [n][d][r]; 1 KB per call
            #pragma unroll
            for (int c = 0; c < 4; ++c) {
                const int kc = c * 4 + wave;
                async16(&Bs[kc * 512],
                        Ub + (size_t)(nb + kc) * (DMODEL * RANK)
                           + (size_t)(bn * 64 + lane) * RANK);
            }
            __syncthreads();
            #pragma unroll
            for (int s = 0; s < 4; ++s) {
                const int kc = s * 4 + lq;
                bf16x8 af[2], bfr[2];
                #pragma unroll
                for (int i = 0; i < 2; ++i) {
                    const int m = wm * 32 + i * 16 + l15;
                    af[i] = *(const bf16x8*)&As[m * 128 + ((kc ^ (m & 15)) * 8)];
                }
                #pragma unroll
                for (int j = 0; j < 2; ++j) {
                    const int n = wn * 32 + j * 16 + l15;
                    bfr[j] = *(const bf16x8*)&Bs[kc * 512 + n * 8];
                }
                #pragma unroll
                for (int i = 0; i < 2; ++i)
                    #pragma unroll
                    for (int j = 0; j < 2; ++j)
                        acc[i][j] = __builtin_amdgcn_mfma_f32_16x16x32_bf16(
                            af[i], bfr[j], acc[i][j], 0, 0, 0);
            }
            __syncthreads();
        }
        #pragma unroll
        for (int i = 0; i < 2; ++i) {
            const int rowb = bm * 64 + wm * 32 + i * 16 + lq * 4;
            #pragma unroll
            for (int j = 0; j < 2; ++j) {
                const int col = bn * 64 + wn * 32 + j * 16 + l15;
                #pragma unroll
                for (int r = 0; r < 4; ++r)
                    out[(size_t)(rowb + r) * DMODEL + col] = acc[i][j][r];
            }
        }
    }
}

extern "C" void kernel_launch(void* const* d_in, const int* in_sizes, int n_in,
                              void* d_out, int out_size, void* d_ws, size_t ws_size,
                              hipStream_t stream) {
    const float* x    = (const float*)d_in[0];
    const float* V    = (const float*)d_in[1];
    const float* U    = (const float*)d_in[2];
    const float* enc  = (const float*)d_in[3];
    const float* bias = (const float*)d_in[4];

    float* out  = (float*)d_out;                       // [4096,1024]
    float* gate = out + (size_t)BATCHN * DMODEL;       // [4096,64] fp32
    float* fro  = gate + (size_t)BATCHN * NT;          // [64]

    char* ws = (char*)d_ws;
    unsigned short* xb = (unsigned short*)ws;                    // 8,388,608 B
    unsigned short* Wb = (unsigned short*)(ws + 8388608);        // 1,179,648 B
    unsigned short* Ub = (unsigned short*)(ws + 9568256);        // 1,048,576 B
    unsigned short* vx = (unsigned short*)(ws + 10616832);       // 4,194,304 B
    unsigned* counters = (unsigned*)(ws + 14811136);             // 8 B

    hipMemsetAsync(counters, 0, 2 * sizeof(unsigned), stream);
    fused_kernel<<<1024, 256, 0, stream>>>(x, V, U, enc, bias, out, gate, fro,
                                           xb, Wb, Ub, vx, counters);
}